// Round 1
// baseline (1794.253 us; speedup 1.0000x reference)
//
#include <hip/hip_runtime.h>
#include <cstddef>
#include <cstdint>

#define H 256
#define NMOL 512
#define NB 256
#define MN (NMOL * NB)   // 131072

constexpr float SCALE_F = 0.0625f;     // 256^-0.5
constexpr float GAMMA_F = 0.96875f;    // 1 - 2^-5
constexpr float EPS_F   = 1e-5f;

// ---------------- wave/block reduce helpers ----------------
__device__ __forceinline__ float wave_max(float v) {
#pragma unroll
  for (int o = 32; o; o >>= 1) v = fmaxf(v, __shfl_xor(v, o));
  return v;
}
__device__ __forceinline__ float wave_sum(float v) {
#pragma unroll
  for (int o = 32; o; o >>= 1) v += __shfl_xor(v, o);
  return v;
}

// ---------------- tiled fp32 GEMM:  C[i,j] = sum_c A[i,c] * W[j,c]  ----------------
// MODE 0: plain                       (q,k,v GEMMs)
// MODE 1: A-elem scaled by GK[mol,c]; epilogue += Q, ReLU   (ret GEMM; C may alias Q)
// MODE 2: epilogue += bias[j]                                (out GEMM)
#define TS 64
#define KS 16
#define LDP 68   // 68 floats = 272B = 17*16B -> float4-aligned rows, rotating banks

template <int MODE>
__global__ __launch_bounds__(256) void gemm_k(
    const float* __restrict__ A, const float* __restrict__ W,
    float* C, const float* __restrict__ bias,
    const float* Q, const float* __restrict__ GK)
{
  __shared__ __align__(16) float As[KS][LDP];
  __shared__ __align__(16) float Ws[KS][LDP];
  const int row0 = blockIdx.x * TS;
  const int col0 = blockIdx.y * TS;
  const int tid  = threadIdx.x;
  const int tx = tid & 15, ty = tid >> 4;
  const int lr = tid >> 2;         // load row 0..63
  const int lk = (tid & 3) * 4;    // 0,4,8,12
  const int mol = row0 >> 8;       // 64-row tile lies inside one molecule
  const float* gkrow = (MODE == 1) ? (GK + (size_t)mol * H) : nullptr;

  float acc[4][4] = {};

  for (int k0 = 0; k0 < H; k0 += KS) {
    float4 a4 = *reinterpret_cast<const float4*>(A + (size_t)(row0 + lr) * H + k0 + lk);
    if (MODE == 1) {
      a4.x *= gkrow[k0 + lk + 0];
      a4.y *= gkrow[k0 + lk + 1];
      a4.z *= gkrow[k0 + lk + 2];
      a4.w *= gkrow[k0 + lk + 3];
    }
    float4 w4 = *reinterpret_cast<const float4*>(W + (size_t)(col0 + lr) * H + k0 + lk);
    __syncthreads();   // previous iteration's LDS reads done
    As[lk + 0][lr] = a4.x; As[lk + 1][lr] = a4.y; As[lk + 2][lr] = a4.z; As[lk + 3][lr] = a4.w;
    Ws[lk + 0][lr] = w4.x; Ws[lk + 1][lr] = w4.y; Ws[lk + 2][lr] = w4.z; Ws[lk + 3][lr] = w4.w;
    __syncthreads();
#pragma unroll
    for (int kk = 0; kk < KS; ++kk) {
      float4 av = *reinterpret_cast<const float4*>(&As[kk][ty * 4]);
      float4 bv = *reinterpret_cast<const float4*>(&Ws[kk][tx * 4]);
      float a[4] = {av.x, av.y, av.z, av.w};
      float b[4] = {bv.x, bv.y, bv.z, bv.w};
#pragma unroll
      for (int i = 0; i < 4; ++i)
#pragma unroll
        for (int j = 0; j < 4; ++j)
          acc[i][j] = fmaf(a[i], b[j], acc[i][j]);
    }
  }

#pragma unroll
  for (int i = 0; i < 4; ++i) {
    const int r = row0 + ty * 4 + i;
#pragma unroll
    for (int j = 0; j < 4; ++j) {
      const int c = col0 + tx * 4 + j;
      float x = acc[i][j];
      if (MODE == 1) { x += Q[(size_t)r * H + c]; x = fmaxf(x, 0.f); }
      if (MODE == 2) { x += bias[c]; }
      C[(size_t)r * H + c] = x;
    }
  }
}

// ---------------- per-molecule: softmax over h, gq, and k column sums ----------------
__global__ __launch_bounds__(256) void gq_kernel(
    const float* __restrict__ q, const float* __restrict__ k,
    const float* __restrict__ walpha,
    float* __restrict__ gq, float* __restrict__ S1, float* __restrict__ S2)
{
  __shared__ float red[4];
  const int m = blockIdx.x, t = threadIdx.x;
  const float wa = walpha[t] * SCALE_F;
  const float* qm = q + (size_t)m * NB * H;
  const float* km = k + (size_t)m * NB * H;
  float acc = 0.f, s1 = 0.f, s2 = 0.f;
  for (int n = 0; n < NB; ++n) {
    const float qv = qm[n * H + t];
    const float kv = km[n * H + t];
    s1 += kv;
    s2 = fmaf(kv, kv, s2);
    const float s = qv * wa;
    // block max over h
    float mx = wave_max(s);
    if ((t & 63) == 0) red[t >> 6] = mx;
    __syncthreads();
    mx = fmaxf(fmaxf(red[0], red[1]), fmaxf(red[2], red[3]));
    __syncthreads();
    const float e = expf(s - mx);
    float sm = wave_sum(e);
    if ((t & 63) == 0) red[t >> 6] = sm;
    __syncthreads();
    sm = red[0] + red[1] + red[2] + red[3];
    __syncthreads();
    acc = fmaf(e / sm, qv, acc);
  }
  gq[m * H + t] = acc;
  S1[m * H + t] = s1;
  S2[m * H + t] = s2;
}

// ---------------- per-molecule: corr (truncated decay scan) + gk ----------------
// corr[m] = sum_{t=0..min(3,m)} decay^t * (gq[m]^T K[m-t]) @ V[m-t]
// gk[m,h] = w_beta[h]*S*gq^2*S2 + gamma^(m+1)*corr*gq*S1
__global__ __launch_bounds__(256) void corr_gk_kernel(
    const float* __restrict__ k, const float* __restrict__ v,
    const float* __restrict__ gq, const float* __restrict__ S1,
    const float* __restrict__ S2, const float* __restrict__ wbeta,
    float* __restrict__ gk)
{
  __shared__ float sgq[H];
  __shared__ float su[H];
  const int m = blockIdx.x, t = threadIdx.x;
  sgq[t] = gq[m * H + t];
  __syncthreads();

  const float decay = powf(GAMMA_F, 256.0f);   // ~2.9526e-4
  float corr = 0.f;
  float dp = 1.f;
  const int tmax = m < 3 ? m : 3;
  for (int tt = 0; tt <= tmax; ++tt) {
    const float* kb = k + (size_t)(m - tt) * NB * H;
    const float* vb = v + (size_t)(m - tt) * NB * H;
    float u = 0.f;
    for (int c = 0; c < NB; ++c) u = fmaf(sgq[c], kb[c * H + t], u);
    __syncthreads();         // su reads from previous tt done
    su[t] = u;
    __syncthreads();
    float a = 0.f;
    for (int e = 0; e < NB; ++e) a = fmaf(su[e], vb[e * H + t], a);
    corr = fmaf(dp, a, corr);
    dp *= decay;
  }
  const float gqv  = sgq[t];
  const float gseq = powf(GAMMA_F, (float)(m + 1));
  const float g = wbeta[t] * SCALE_F * gqv * gqv * S2[m * H + t]
                + gseq * corr * gqv * S1[m * H + t];
  gk[m * H + t] = g;
}

// ---------------- GroupNorm(8 groups over n) in place on d_out rows 1.. ----------------
__global__ __launch_bounds__(256) void gn_kernel(
    float* out, const float* __restrict__ gnw, const float* __restrict__ gnb)
{
  __shared__ float red[4];
  const int m = blockIdx.x >> 3;
  const int g = blockIdx.x & 7;
  const int t = threadIdx.x;
  float* base = out + ((size_t)m * NB + g * 32) * H;
  float s = 0.f, s2 = 0.f;
  float xs[32];
#pragma unroll
  for (int i = 0; i < 32; ++i) {
    const float x = base[i * H + t];
    xs[i] = x;
    s += x;
    s2 = fmaf(x, x, s2);
  }
  float w = wave_sum(s);
  if ((t & 63) == 0) red[t >> 6] = w;
  __syncthreads();
  s = red[0] + red[1] + red[2] + red[3];
  __syncthreads();
  w = wave_sum(s2);
  if ((t & 63) == 0) red[t >> 6] = w;
  __syncthreads();
  s2 = red[0] + red[1] + red[2] + red[3];

  const float mu  = s * (1.f / 8192.f);
  const float var = s2 * (1.f / 8192.f) - mu * mu;
  const float inv = rsqrtf(var + EPS_F);
#pragma unroll
  for (int i = 0; i < 32; ++i) {
    const int n = g * 32 + i;
    base[i * H + t] = (xs[i] - mu) * inv * gnw[n] + gnb[n];
  }
}

// ---------------- launch ----------------
extern "C" void kernel_launch(void* const* d_in, const int* in_sizes, int n_in,
                              void* d_out, int out_size, void* d_ws, size_t ws_size,
                              hipStream_t stream)
{
  (void)in_sizes; (void)n_in; (void)out_size; (void)ws_size;
  const float* msg    = (const float*)d_in[0];
  const float* Wq     = (const float*)d_in[1];
  const float* Wk     = (const float*)d_in[2];
  const float* Wv     = (const float*)d_in[3];
  const float* Wr     = (const float*)d_in[4];
  const float* Wo     = (const float*)d_in[5];
  const float* bo     = (const float*)d_in[6];
  const float* walpha = (const float*)d_in[7];
  const float* wbeta  = (const float*)d_in[8];
  const float* gnw    = (const float*)d_in[9];
  const float* gnb    = (const float*)d_in[10];
  float* out = (float*)d_out;

  float* q  = (float*)d_ws;
  float* k  = q  + (size_t)MN * H;
  float* v  = k  + (size_t)MN * H;
  float* gq = v  + (size_t)MN * H;
  float* S1 = gq + (size_t)NMOL * H;
  float* S2 = S1 + (size_t)NMOL * H;
  float* gk = S2 + (size_t)NMOL * H;

  const dim3 gg(MN / TS, H / TS);
  const dim3 bb(256);

  gemm_k<0><<<gg, bb, 0, stream>>>(msg, Wq, q, nullptr, nullptr, nullptr);
  gemm_k<0><<<gg, bb, 0, stream>>>(msg, Wk, k, nullptr, nullptr, nullptr);
  gemm_k<0><<<gg, bb, 0, stream>>>(msg, Wv, v, nullptr, nullptr, nullptr);

  gq_kernel<<<NMOL, bb, 0, stream>>>(q, k, walpha, gq, S1, S2);
  corr_gk_kernel<<<NMOL, bb, 0, stream>>>(k, v, gq, S1, S2, wbeta, gk);

  // ret = relu((gk ⊙ v) @ Wr^T + q), overwrites q workspace (tile-local RAW)
  gemm_k<1><<<gg, bb, 0, stream>>>(v, Wr, q, nullptr, q, gk);
  // out = ret @ Wo^T + b_o  -> d_out rows 1..MN
  gemm_k<2><<<gg, bb, 0, stream>>>(q, Wo, out + H, bo, nullptr, nullptr);

  // row 0 = cached zero vector
  (void)hipMemsetAsync(d_out, 0, H * sizeof(float), stream);

  gn_kernel<<<NMOL * 8, bb, 0, stream>>>(out + H, gnw, gnb);
}

// Round 2
// 772.898 us; speedup vs baseline: 2.3215x; 2.3215x over previous
//
#include <hip/hip_runtime.h>
#include <cstddef>
#include <cstdint>

#define H 256
#define NMOL 512
#define NB 256
#define MN (NMOL * NB)   // 131072

typedef unsigned short ushort_t;
typedef __attribute__((ext_vector_type(8))) __bf16 bf16x8;
typedef __attribute__((ext_vector_type(4))) float f32x4;
typedef __attribute__((ext_vector_type(8))) unsigned short u16x8;

constexpr float SCALE_F = 0.0625f;     // 256^-0.5
constexpr float GAMMA_F = 0.96875f;    // 1 - 2^-5
constexpr float EPS_F   = 1e-5f;

__device__ __forceinline__ float wave_max(float v) {
#pragma unroll
  for (int o = 32; o; o >>= 1) v = fmaxf(v, __shfl_xor(v, o));
  return v;
}
__device__ __forceinline__ float wave_sum(float v) {
#pragma unroll
  for (int o = 32; o; o >>= 1) v += __shfl_xor(v, o);
  return v;
}
__device__ __forceinline__ ushort_t f2bf(float f) {
  unsigned u = __builtin_bit_cast(unsigned, f);
  return (ushort_t)((u + 0x7FFFu + ((u >> 16) & 1u)) >> 16);
}

// =======================  bf16 MFMA GEMM  =======================
// C[i,j] = sum_c A[i,c] * W[j,c]      (A [M,256], W [256,256] both row-major)
// MODE 0: A fp32 (convert in staging), C fp32                       -> q,k,v
// MODE 1: A fp32 scaled by GK[mol,c]; epi: +Qres, ReLU; C bf16      -> ret
// MODE 2: A bf16; epi: +bias[j]; C fp32                             -> out
#define BM 128
#define BN 128
#define BK 32
#define LDK 40   // padded k-stride (bf16 elems): 80B rows, 16B-aligned, bank-rotating

template <int MODE>
__global__ __launch_bounds__(256) void mfma_gemm(
    const void* __restrict__ Av, const ushort_t* __restrict__ W,
    void* __restrict__ Cv, const float* __restrict__ bias,
    const float* __restrict__ Qres, const float* __restrict__ GK)
{
  __shared__ __align__(16) __bf16 As[BM][LDK];
  __shared__ __align__(16) __bf16 Bs[BN][LDK];
  const int tid  = threadIdx.x;
  const int row0 = blockIdx.x * BM;
  const int col0 = blockIdx.y * BN;
  const int lane = tid & 63;
  const int wid  = tid >> 6;
  const int wm = (wid & 1) * 64, wn = (wid >> 1) * 64;
  const int fr = lane & 15;          // fragment row/col
  const int ko = (lane >> 4) * 8;    // fragment k offset
  // staging: thread t loads 16 consecutive k-elems of one row (two 16B LDS chunks)
  const int ra = tid >> 1;           // 0..127
  const int kb = (tid & 1) * 16;     // 0 or 16
  const int mol = row0 >> 8;         // BM=128 divides 256 -> tile inside one molecule

  f32x4 acc[4][4] = {};

  for (int k0 = 0; k0 < H; k0 += BK) {
    u16x8 apk0, apk1, bpk0, bpk1;
    if (MODE == 2) {   // bf16 A
      const ushort_t* src = (const ushort_t*)Av + (size_t)(row0 + ra) * H + k0 + kb;
      apk0 = *reinterpret_cast<const u16x8*>(src);
      apk1 = *reinterpret_cast<const u16x8*>(src + 8);
    } else {           // fp32 A (+ optional scale)
      const float* src = (const float*)Av + (size_t)(row0 + ra) * H + k0 + kb;
      float a[16];
#pragma unroll
      for (int j = 0; j < 4; ++j)
        *reinterpret_cast<float4*>(&a[j * 4]) = *reinterpret_cast<const float4*>(src + j * 4);
      if (MODE == 1) {
        const float* g = GK + (size_t)mol * H + k0 + kb;
#pragma unroll
        for (int j = 0; j < 16; ++j) a[j] *= g[j];
      }
#pragma unroll
      for (int j = 0; j < 8; ++j) { apk0[j] = f2bf(a[j]); apk1[j] = f2bf(a[j + 8]); }
    }
    {
      const ushort_t* src = W + (size_t)(col0 + ra) * H + k0 + kb;
      bpk0 = *reinterpret_cast<const u16x8*>(src);
      bpk1 = *reinterpret_cast<const u16x8*>(src + 8);
    }
    __syncthreads();   // previous iteration's LDS reads complete
    *reinterpret_cast<u16x8*>(&As[ra][kb])     = apk0;
    *reinterpret_cast<u16x8*>(&As[ra][kb + 8]) = apk1;
    *reinterpret_cast<u16x8*>(&Bs[ra][kb])     = bpk0;
    *reinterpret_cast<u16x8*>(&Bs[ra][kb + 8]) = bpk1;
    __syncthreads();

    bf16x8 af[4], bfr[4];
#pragma unroll
    for (int mf = 0; mf < 4; ++mf)
      af[mf] = *reinterpret_cast<const bf16x8*>(&As[wm + mf * 16 + fr][ko]);
#pragma unroll
    for (int nf = 0; nf < 4; ++nf)
      bfr[nf] = *reinterpret_cast<const bf16x8*>(&Bs[wn + nf * 16 + fr][ko]);
#pragma unroll
    for (int mf = 0; mf < 4; ++mf)
#pragma unroll
      for (int nf = 0; nf < 4; ++nf)
        acc[mf][nf] = __builtin_amdgcn_mfma_f32_16x16x32_bf16(af[mf], bfr[nf], acc[mf][nf], 0, 0, 0);
  }

  // D layout: col = lane&15, row = (lane>>4)*4 + j
#pragma unroll
  for (int mf = 0; mf < 4; ++mf) {
    const int rr0 = row0 + wm + mf * 16 + (lane >> 4) * 4;
#pragma unroll
    for (int nf = 0; nf < 4; ++nf) {
      const int cc = col0 + wn + nf * 16 + fr;
#pragma unroll
      for (int j = 0; j < 4; ++j) {
        const size_t idx = (size_t)(rr0 + j) * H + cc;
        float x = acc[mf][nf][j];
        if (MODE == 0) {
          ((float*)Cv)[idx] = x;
        } else if (MODE == 1) {
          x += Qres[idx];
          x = fmaxf(x, 0.f);
          ((ushort_t*)Cv)[idx] = f2bf(x);
        } else {
          ((float*)Cv)[idx] = x + bias[cc];
        }
      }
    }
  }
}

// =======================  weight fp32 -> bf16 (5 mats)  =======================
__global__ __launch_bounds__(256) void cvt5_kernel(
    const float* __restrict__ w0, const float* __restrict__ w1,
    const float* __restrict__ w2, const float* __restrict__ w3,
    const float* __restrict__ w4, ushort_t* __restrict__ out)
{
  const int id = blockIdx.x * 256 + threadIdx.x;   // 81920 threads, 4 elems each
  const int w = id >> 14;                           // / 16384
  const int off = (id & 16383) * 4;
  const float* src = (w == 0) ? w0 : (w == 1) ? w1 : (w == 2) ? w2 : (w == 3) ? w3 : w4;
  const float4 v = *reinterpret_cast<const float4*>(src + off);
  ushort4 o;
  o.x = f2bf(v.x); o.y = f2bf(v.y); o.z = f2bf(v.z); o.w = f2bf(v.w);
  *reinterpret_cast<ushort4*>(out + (size_t)w * 65536 + off) = o;
}

// =======================  gq: softmax over h + column sums  =======================
// 1024 threads = 16 waves; wave w owns rows n = w*16..w*16+15; lane l owns h = 4l..4l+3
__global__ __launch_bounds__(1024) void gq_kernel(
    const float* __restrict__ q, const float* __restrict__ k,
    const float* __restrict__ walpha,
    float* __restrict__ gq, float* __restrict__ S1, float* __restrict__ S2)
{
  __shared__ float red[16][H];
  const int m = blockIdx.x;
  const int tid = threadIdx.x;
  const int w = tid >> 6, l = tid & 63;
  const int h0 = l * 4;
  float4 wa = *reinterpret_cast<const float4*>(walpha + h0);
  wa.x *= SCALE_F; wa.y *= SCALE_F; wa.z *= SCALE_F; wa.w *= SCALE_F;
  const float* qm = q + (size_t)m * NB * H;
  const float* km = k + (size_t)m * NB * H;
  float4 acc = {0, 0, 0, 0}, s1 = {0, 0, 0, 0}, s2 = {0, 0, 0, 0};
#pragma unroll 2
  for (int i = 0; i < 16; ++i) {
    const int n = w * 16 + i;
    const float4 qv = *reinterpret_cast<const float4*>(qm + (size_t)n * H + h0);
    const float4 kv = *reinterpret_cast<const float4*>(km + (size_t)n * H + h0);
    s1.x += kv.x; s1.y += kv.y; s1.z += kv.z; s1.w += kv.w;
    s2.x = fmaf(kv.x, kv.x, s2.x); s2.y = fmaf(kv.y, kv.y, s2.y);
    s2.z = fmaf(kv.z, kv.z, s2.z); s2.w = fmaf(kv.w, kv.w, s2.w);
    float4 s;
    s.x = qv.x * wa.x; s.y = qv.y * wa.y; s.z = qv.z * wa.z; s.w = qv.w * wa.w;
    float mx = wave_max(fmaxf(fmaxf(s.x, s.y), fmaxf(s.z, s.w)));
    float4 e;
    e.x = expf(s.x - mx); e.y = expf(s.y - mx); e.z = expf(s.z - mx); e.w = expf(s.w - mx);
    const float sm = wave_sum((e.x + e.y) + (e.z + e.w));
    const float inv = 1.0f / sm;
    acc.x = fmaf(e.x * inv, qv.x, acc.x); acc.y = fmaf(e.y * inv, qv.y, acc.y);
    acc.z = fmaf(e.z * inv, qv.z, acc.z); acc.w = fmaf(e.w * inv, qv.w, acc.w);
  }
  // combine 16 wave-partials (three rounds through the same LDS buffer)
  *reinterpret_cast<float4*>(&red[w][h0]) = acc;
  __syncthreads();
  if (tid < H) {
    float s = 0;
#pragma unroll
    for (int ww = 0; ww < 16; ++ww) s += red[ww][tid];
    gq[(size_t)m * H + tid] = s;
  }
  __syncthreads();
  *reinterpret_cast<float4*>(&red[w][h0]) = s1;
  __syncthreads();
  if (tid < H) {
    float s = 0;
#pragma unroll
    for (int ww = 0; ww < 16; ++ww) s += red[ww][tid];
    S1[(size_t)m * H + tid] = s;
  }
  __syncthreads();
  *reinterpret_cast<float4*>(&red[w][h0]) = s2;
  __syncthreads();
  if (tid < H) {
    float s = 0;
#pragma unroll
    for (int ww = 0; ww < 16; ++ww) s += red[ww][tid];
    S2[(size_t)m * H + tid] = s;
  }
}

// =======================  corr (truncated decay scan) + gk  =======================
__global__ __launch_bounds__(256) void corr_gk_kernel(
    const float* __restrict__ k, const float* __restrict__ v,
    const float* __restrict__ gq, const float* __restrict__ S1,
    const float* __restrict__ S2, const float* __restrict__ wbeta,
    float* __restrict__ gk)
{
  __shared__ float sgq[H];
  __shared__ float su[H];
  const int m = blockIdx.x, t = threadIdx.x;
  sgq[t] = gq[(size_t)m * H + t];
  __syncthreads();

  const float decay = powf(GAMMA_F, 256.0f);   // ~2.9525e-4; decay^3 negligible
  float corr = 0.f, dp = 1.f;
  const int tmax = m < 2 ? m : 2;
  for (int tt = 0; tt <= tmax; ++tt) {
    const float* kb = k + (size_t)(m - tt) * NB * H;
    const float* vb = v + (size_t)(m - tt) * NB * H;
    float u0 = 0, u1 = 0, u2 = 0, u3 = 0;
    for (int c = 0; c < NB; c += 4) {
      u0 = fmaf(sgq[c + 0], kb[(c + 0) * H + t], u0);
      u1 = fmaf(sgq[c + 1], kb[(c + 1) * H + t], u1);
      u2 = fmaf(sgq[c + 2], kb[(c + 2) * H + t], u2);
      u3 = fmaf(sgq[c + 3], kb[(c + 3) * H + t], u3);
    }
    __syncthreads();
    su[t] = (u0 + u1) + (u2 + u3);
    __syncthreads();
    float a0 = 0, a1 = 0, a2 = 0, a3 = 0;
    for (int e = 0; e < NB; e += 4) {
      a0 = fmaf(su[e + 0], vb[(e + 0) * H + t], a0);
      a1 = fmaf(su[e + 1], vb[(e + 1) * H + t], a1);
      a2 = fmaf(su[e + 2], vb[(e + 2) * H + t], a2);
      a3 = fmaf(su[e + 3], vb[(e + 3) * H + t], a3);
    }
    corr = fmaf(dp, (a0 + a1) + (a2 + a3), corr);
    dp *= decay;
  }
  const float gqv  = sgq[t];
  const float gseq = powf(GAMMA_F, (float)(m + 1));
  gk[(size_t)m * H + t] = wbeta[t] * SCALE_F * gqv * gqv * S2[(size_t)m * H + t]
                        + gseq * corr * gqv * S1[(size_t)m * H + t];
}

// =======================  GroupNorm (8 groups over n), in place  =======================
__global__ __launch_bounds__(256) void gn_kernel(
    float* out, const float* __restrict__ gnw, const float* __restrict__ gnb)
{
  __shared__ float redm[4], redv[4];
  const int m = blockIdx.x >> 3;
  const int g = blockIdx.x & 7;
  const int t = threadIdx.x;
  const int hc = (t & 63) * 4;     // col chunk
  const int r0 = (t >> 6) * 8;     // 8 rows per thread
  float* base = out + ((size_t)m * NB + g * 32) * H;
  float4 xs[8];
  float s = 0.f, s2 = 0.f;
#pragma unroll
  for (int i = 0; i < 8; ++i) {
    const float4 x = *reinterpret_cast<const float4*>(base + (size_t)(r0 + i) * H + hc);
    xs[i] = x;
    s += (x.x + x.y) + (x.z + x.w);
    s2 = fmaf(x.x, x.x, s2); s2 = fmaf(x.y, x.y, s2);
    s2 = fmaf(x.z, x.z, s2); s2 = fmaf(x.w, x.w, s2);
  }
  const float ws = wave_sum(s);
  const float ws2 = wave_sum(s2);
  if ((t & 63) == 0) { redm[t >> 6] = ws; redv[t >> 6] = ws2; }
  __syncthreads();
  s  = (redm[0] + redm[1]) + (redm[2] + redm[3]);
  s2 = (redv[0] + redv[1]) + (redv[2] + redv[3]);

  const float mu  = s * (1.f / 8192.f);
  const float var = s2 * (1.f / 8192.f) - mu * mu;
  const float inv = rsqrtf(var + EPS_F);
#pragma unroll
  for (int i = 0; i < 8; ++i) {
    const int n = g * 32 + r0 + i;
    const float wgt = gnw[n] * inv, b = gnb[n];
    float4 x = xs[i];
    x.x = (x.x - mu) * wgt + b; x.y = (x.y - mu) * wgt + b;
    x.z = (x.z - mu) * wgt + b; x.w = (x.w - mu) * wgt + b;
    *reinterpret_cast<float4*>(base + (size_t)(r0 + i) * H + hc) = x;
  }
}

// =======================  launch  =======================
extern "C" void kernel_launch(void* const* d_in, const int* in_sizes, int n_in,
                              void* d_out, int out_size, void* d_ws, size_t ws_size,
                              hipStream_t stream)
{
  (void)in_sizes; (void)n_in; (void)out_size; (void)ws_size;
  const float* msg    = (const float*)d_in[0];
  const float* Wq     = (const float*)d_in[1];
  const float* Wk     = (const float*)d_in[2];
  const float* Wv     = (const float*)d_in[3];
  const float* Wr     = (const float*)d_in[4];
  const float* Wo     = (const float*)d_in[5];
  const float* bo     = (const float*)d_in[6];
  const float* walpha = (const float*)d_in[7];
  const float* wbeta  = (const float*)d_in[8];
  const float* gnw    = (const float*)d_in[9];
  const float* gnb    = (const float*)d_in[10];
  float* out = (float*)d_out;

  float* q  = (float*)d_ws;                  // [MN,H] f32
  float* k  = q  + (size_t)MN * H;           // [MN,H] f32
  float* v  = k  + (size_t)MN * H;           // [MN,H] f32
  float* gq = v  + (size_t)MN * H;           // [NMOL,H]
  float* S1 = gq + (size_t)NMOL * H;
  float* S2 = S1 + (size_t)NMOL * H;
  float* gk = S2 + (size_t)NMOL * H;
  ushort_t* retb = (ushort_t*)(gk + (size_t)NMOL * H);  // [MN,H] bf16
  ushort_t* wbf  = retb + (size_t)MN * H;               // 5x[H,H] bf16

  const dim3 bb(256);
  cvt5_kernel<<<320, bb, 0, stream>>>(Wq, Wk, Wv, Wr, Wo, wbf);

  const dim3 gg(MN / BM, H / BN);
  mfma_gemm<0><<<gg, bb, 0, stream>>>(msg, wbf + 0 * 65536, q, nullptr, nullptr, nullptr);
  mfma_gemm<0><<<gg, bb, 0, stream>>>(msg, wbf + 1 * 65536, k, nullptr, nullptr, nullptr);
  mfma_gemm<0><<<gg, bb, 0, stream>>>(msg, wbf + 2 * 65536, v, nullptr, nullptr, nullptr);

  gq_kernel<<<NMOL, dim3(1024), 0, stream>>>(q, k, walpha, gq, S1, S2);
  corr_gk_kernel<<<NMOL, bb, 0, stream>>>(k, v, gq, S1, S2, wbeta, gk);

  // ret = relu((gk ⊙ v) @ Wr^T + q)  -> bf16
  mfma_gemm<1><<<gg, bb, 0, stream>>>(v, wbf + 3 * 65536, retb, nullptr, q, gk);
  // out = ret @ Wo^T + b_o  -> rows 1..MN of d_out
  mfma_gemm<2><<<gg, bb, 0, stream>>>(retb, wbf + 4 * 65536, out + H, bo, nullptr, nullptr);

  (void)hipMemsetAsync(d_out, 0, H * sizeof(float), stream);
  gn_kernel<<<NMOL * 8, bb, 0, stream>>>(out + H, gnw, gnb);
}